// Round 1
// baseline (556.493 us; speedup 1.0000x reference)
//
#include <hip/hip_runtime.h>
#include <hip/hip_bf16.h>
#include <stdint.h>

#define IN_F   4096
#define OUT_F  4096
#define MROWS  8192   // 4 * 2048

typedef __bf16 bf16x8 __attribute__((ext_vector_type(8)));
typedef float  f32x4  __attribute__((ext_vector_type(4)));
typedef unsigned short ushort8v __attribute__((ext_vector_type(8)));

__device__ __constant__ float NF4_TAB[16] = {
    -1.0f, -0.6961928009986877f, -0.5250730514526367f, -0.39491748809814453f,
    -0.28444138169288635f, -0.18477343022823334f, -0.09105003625154495f, 0.0f,
    0.07958029955625534f, 0.16093020141124725f, 0.24611230194568634f, 0.33791524171829224f,
    0.44070982933044434f, 0.5626170039176941f, 0.7229568362236023f, 1.0f,
};

__device__ __forceinline__ unsigned short f2bf_rne(float f) {
    unsigned u = __builtin_bit_cast(unsigned, f);
    return (unsigned short)((u + 0x7FFFu + ((u >> 16) & 1u)) >> 16);
}

// ---------------------------------------------------------------------------
// Kernel 1: NF4 dequant -> bf16 weight matrix [OUT_F][IN_F]
// packed[i] holds one byte: hi nibble -> weight 2i, lo nibble -> weight 2i+1
// absmax block = 64 flat weights = 32 packed entries.
// Each thread: 4 packed (int4 load, 16B) -> 8 bf16 (ushort8 store, 16B).
// ---------------------------------------------------------------------------
__global__ void dequant_nf4_kernel(const int* __restrict__ packed,
                                   const float* __restrict__ absmax,
                                   unsigned short* __restrict__ wout,
                                   int ngroups) {
    int stride = gridDim.x * blockDim.x;
    for (int g = blockIdx.x * blockDim.x + threadIdx.x; g < ngroups; g += stride) {
        int4 pv = reinterpret_cast<const int4*>(packed)[g];
        float am = absmax[g >> 3];   // (g*4) >> 5
        int p0 = pv.x, p1 = pv.y, p2 = pv.z, p3 = pv.w;
        ushort8v o;
        o[0] = f2bf_rne(NF4_TAB[(p0 >> 4) & 0xF] * am);
        o[1] = f2bf_rne(NF4_TAB[ p0       & 0xF] * am);
        o[2] = f2bf_rne(NF4_TAB[(p1 >> 4) & 0xF] * am);
        o[3] = f2bf_rne(NF4_TAB[ p1       & 0xF] * am);
        o[4] = f2bf_rne(NF4_TAB[(p2 >> 4) & 0xF] * am);
        o[5] = f2bf_rne(NF4_TAB[ p2       & 0xF] * am);
        o[6] = f2bf_rne(NF4_TAB[(p3 >> 4) & 0xF] * am);
        o[7] = f2bf_rne(NF4_TAB[ p3       & 0xF] * am);
        *reinterpret_cast<ushort8v*>(&wout[(size_t)g * 8]) = o;
    }
}

// ---------------------------------------------------------------------------
// Kernel 2: f32 -> bf16 (RNE), vectorized float4 in / ushort4 out
// ---------------------------------------------------------------------------
__global__ void cvt_f32_bf16_kernel(const float* __restrict__ in,
                                    unsigned short* __restrict__ out,
                                    int ngroups) {
    int stride = gridDim.x * blockDim.x;
    for (int g = blockIdx.x * blockDim.x + threadIdx.x; g < ngroups; g += stride) {
        float4 v = reinterpret_cast<const float4*>(in)[g];
        ushort4 o;
        o.x = f2bf_rne(v.x);
        o.y = f2bf_rne(v.y);
        o.z = f2bf_rne(v.z);
        o.w = f2bf_rne(v.w);
        reinterpret_cast<ushort4*>(out)[g] = o;
    }
}

// ---------------------------------------------------------------------------
// Kernel 3: bf16 GEMM, C[M][N] = A[M][K] * B[N][K]^T + bias[N]  (both K-major)
// 128x128 tile, BK=32, 256 threads (4 waves, 2x2), each wave 64x64 output
// = 4x4 fragments of mfma_f32_16x16x32_bf16. global_load_lds width-16 staging.
// ---------------------------------------------------------------------------
#define GLOAD16(gp, lp)                                                        \
    __builtin_amdgcn_global_load_lds(                                          \
        (const __attribute__((address_space(1))) void*)(gp),                   \
        (__attribute__((address_space(3))) void*)(lp), 16, 0, 0)

__global__ __launch_bounds__(256) void gemm_bf16_kernel(
        const unsigned short* __restrict__ A,   // [MROWS][IN_F] bf16 bits
        const unsigned short* __restrict__ B,   // [OUT_F][IN_F] bf16 bits
        const float* __restrict__ bias,         // [OUT_F]
        float* __restrict__ C) {                // [MROWS][OUT_F]
    __shared__ __align__(16) unsigned short As[128 * 32];
    __shared__ __align__(16) unsigned short Bs[128 * 32];

    const int tid  = threadIdx.x;
    const int lane = tid & 63;
    const int wave = tid >> 6;
    const int wr = wave >> 1;       // wave row (0..1)
    const int wc = wave & 1;        // wave col (0..1)
    const int lr = lane & 15;       // fragment row/col index
    const int lg = lane >> 4;       // k-group / row-group (0..3)

    const int bn = (blockIdx.x & 31) << 7;   // N/128 = 32
    const int bm = (blockIdx.x >> 5) << 7;   // M/128 = 64

    f32x4 acc[4][4] = {};

    // staging: 2 chunks each of A and B tile per thread, 16B per chunk
    // chunk c (0..511): row = c>>2, k-offset = (c&3)*8 elements
    const int c1 = tid, c2 = tid + 256;
    const int r1 = c1 >> 2, k1 = (c1 & 3) * 8;
    const int r2 = c2 >> 2, k2 = (c2 & 3) * 8;
    const unsigned short* Ag1 = A + (size_t)(bm + r1) * IN_F + k1;
    const unsigned short* Ag2 = A + (size_t)(bm + r2) * IN_F + k2;
    const unsigned short* Bg1 = B + (size_t)(bn + r1) * IN_F + k1;
    const unsigned short* Bg2 = B + (size_t)(bn + r2) * IN_F + k2;

    for (int k0 = 0; k0 < IN_F; k0 += 32) {
        GLOAD16(Ag1 + k0, &As[c1 * 8]);
        GLOAD16(Ag2 + k0, &As[c2 * 8]);
        GLOAD16(Bg1 + k0, &Bs[c1 * 8]);
        GLOAD16(Bg2 + k0, &Bs[c2 * 8]);
        __syncthreads();   // compiler drains vmcnt before s_barrier

        bf16x8 af[4], bfv[4];
#pragma unroll
        for (int mi = 0; mi < 4; ++mi)
            af[mi] = *reinterpret_cast<const bf16x8*>(
                &As[(wr * 64 + mi * 16 + lr) * 32 + lg * 8]);
#pragma unroll
        for (int ni = 0; ni < 4; ++ni)
            bfv[ni] = *reinterpret_cast<const bf16x8*>(
                &Bs[(wc * 64 + ni * 16 + lr) * 32 + lg * 8]);

#pragma unroll
        for (int mi = 0; mi < 4; ++mi)
#pragma unroll
            for (int ni = 0; ni < 4; ++ni)
                acc[mi][ni] = __builtin_amdgcn_mfma_f32_16x16x32_bf16(
                    af[mi], bfv[ni], acc[mi][ni], 0, 0, 0);

        __syncthreads();
    }

    // epilogue: C/D layout col = lane&15, row = (lane>>4)*4 + reg
#pragma unroll
    for (int mi = 0; mi < 4; ++mi) {
        const int row0 = bm + wr * 64 + mi * 16 + lg * 4;
#pragma unroll
        for (int ni = 0; ni < 4; ++ni) {
            const int col = bn + wc * 64 + ni * 16 + lr;
            const float bs = bias[col];
            float* cp = C + (size_t)row0 * OUT_F + col;
#pragma unroll
            for (int j = 0; j < 4; ++j)
                cp[(size_t)j * OUT_F] = acc[mi][ni][j] + bs;
        }
    }
}

// ---------------------------------------------------------------------------
extern "C" void kernel_launch(void* const* d_in, const int* in_sizes, int n_in,
                              void* d_out, int out_size, void* d_ws, size_t ws_size,
                              hipStream_t stream) {
    const float* x      = (const float*)d_in[0];
    const int*   packed = (const int*)d_in[1];
    const float* absmax = (const float*)d_in[2];
    const float* bias   = (const float*)d_in[3];
    float* out = (float*)d_out;

    // workspace layout: Wb bf16 [OUT_F*IN_F] (32 MiB) | Xb bf16 [MROWS*IN_F] (64 MiB)
    unsigned short* Wb = (unsigned short*)d_ws;
    unsigned short* Xb = Wb + (size_t)OUT_F * IN_F;

    const int npacked_groups = (OUT_F * IN_F / 2) / 4;   // 2,097,152
    const int ncvt_groups    = (MROWS * IN_F) / 4;       // 8,388,608

    dequant_nf4_kernel<<<2048, 256, 0, stream>>>(packed, absmax, Wb, npacked_groups);
    cvt_f32_bf16_kernel<<<2048, 256, 0, stream>>>(x, Xb, ncvt_groups);
    gemm_bf16_kernel<<<dim3(2048), dim3(256), 0, stream>>>(Xb, Wb, bias, out);
}

// Round 2
// 508.427 us; speedup vs baseline: 1.0945x; 1.0945x over previous
//
#include <hip/hip_runtime.h>
#include <hip/hip_bf16.h>
#include <stdint.h>

#define IN_F   4096
#define OUT_F  4096
#define MROWS  8192   // 4 * 2048
#define NT     64     // K-tiles of BK=64

typedef __bf16 bf16x8 __attribute__((ext_vector_type(8)));
typedef float  f32x4  __attribute__((ext_vector_type(4)));
typedef unsigned short ushort8v __attribute__((ext_vector_type(8)));

__device__ __constant__ float NF4_TAB[16] = {
    -1.0f, -0.6961928009986877f, -0.5250730514526367f, -0.39491748809814453f,
    -0.28444138169288635f, -0.18477343022823334f, -0.09105003625154495f, 0.0f,
    0.07958029955625534f, 0.16093020141124725f, 0.24611230194568634f, 0.33791524171829224f,
    0.44070982933044434f, 0.5626170039176941f, 0.7229568362236023f, 1.0f,
};

__device__ __forceinline__ unsigned short f2bf_rne(float f) {
    unsigned u = __builtin_bit_cast(unsigned, f);
    return (unsigned short)((u + 0x7FFFu + ((u >> 16) & 1u)) >> 16);
}

// ---------------------------------------------------------------------------
// Fused prep: blocks [0,512) dequant NF4 -> bf16 W; blocks [512,2048) f32->bf16 X
// ---------------------------------------------------------------------------
__global__ __launch_bounds__(256) void prep_kernel(
        const float* __restrict__ x, const int* __restrict__ packed,
        const float* __restrict__ absmax,
        unsigned short* __restrict__ Wb, unsigned short* __restrict__ Xb) {
    __shared__ float tab[16];
    if (threadIdx.x < 16) tab[threadIdx.x] = NF4_TAB[threadIdx.x];
    __syncthreads();

    const int bid = blockIdx.x;
    if (bid < 512) {
        // dequant: group = 4 packed ints (each one byte-value) -> 8 bf16
        const int ngroups = OUT_F * IN_F / 8;   // 2,097,152
        const int stride = 512 * 256;
        for (int g = bid * 256 + threadIdx.x; g < ngroups; g += stride) {
            int4 pv = reinterpret_cast<const int4*>(packed)[g];
            float am = absmax[g >> 3];
            ushort8v o;
            o[0] = f2bf_rne(tab[(pv.x >> 4) & 0xF] * am);
            o[1] = f2bf_rne(tab[ pv.x       & 0xF] * am);
            o[2] = f2bf_rne(tab[(pv.y >> 4) & 0xF] * am);
            o[3] = f2bf_rne(tab[ pv.y       & 0xF] * am);
            o[4] = f2bf_rne(tab[(pv.z >> 4) & 0xF] * am);
            o[5] = f2bf_rne(tab[ pv.z       & 0xF] * am);
            o[6] = f2bf_rne(tab[(pv.w >> 4) & 0xF] * am);
            o[7] = f2bf_rne(tab[ pv.w       & 0xF] * am);
            *reinterpret_cast<ushort8v*>(&Wb[(size_t)g * 8]) = o;
        }
    } else {
        // f32 -> bf16, 8 floats per thread-iteration
        const int ngroups = MROWS * IN_F / 8;   // 4,194,304
        const int stride = 1536 * 256;
        for (int g = (bid - 512) * 256 + threadIdx.x; g < ngroups; g += stride) {
            float4 v0 = reinterpret_cast<const float4*>(x)[2 * g];
            float4 v1 = reinterpret_cast<const float4*>(x)[2 * g + 1];
            ushort8v o;
            o[0] = f2bf_rne(v0.x); o[1] = f2bf_rne(v0.y);
            o[2] = f2bf_rne(v0.z); o[3] = f2bf_rne(v0.w);
            o[4] = f2bf_rne(v1.x); o[5] = f2bf_rne(v1.y);
            o[6] = f2bf_rne(v1.z); o[7] = f2bf_rne(v1.w);
            *reinterpret_cast<ushort8v*>(&Xb[(size_t)g * 8]) = o;
        }
    }
}

// ---------------------------------------------------------------------------
// 256x256 8-phase bf16 GEMM (T1+T2+T3+T4+T5), C = A[M][K] * B[N][K]^T + bias
// 512 threads = 8 waves (2 row x 4 col), per-wave out 128x64, BK=64.
// LDS 128 KiB: buf b in {0,1}: A-half kh: b*32768 + kh*8192 ushorts,
//                              B-half kh: b*32768 + 16384 + kh*8192.
// Swizzle (involution): byte X = L ^ (((L>>7)&7)<<4)  [XOR bits 4-6 by bits 7-9]
// -> 16-way ds_read conflict becomes 2-way (free). global_load_lds dest stays
// linear; the global SOURCE address is pre-permuted by the same involution.
// ---------------------------------------------------------------------------
#define GLOAD16(gp, lp)                                                        \
    __builtin_amdgcn_global_load_lds(                                          \
        (const __attribute__((address_space(1))) void*)(gp),                   \
        (__attribute__((address_space(3))) void*)(lp), 16, 0, 0)

#define BAR()   __builtin_amdgcn_s_barrier()
#define LGKM0() do { asm volatile("s_waitcnt lgkmcnt(0)" ::: "memory");        \
                     __builtin_amdgcn_sched_barrier(0); } while (0)
#define VMW(n)  asm volatile("s_waitcnt vmcnt(" #n ")" ::: "memory")

__global__ __launch_bounds__(512) void gemm256_kernel(
        const unsigned short* __restrict__ A,   // [MROWS][IN_F] bf16
        const unsigned short* __restrict__ B,   // [OUT_F][IN_F] bf16
        const float* __restrict__ bias,
        float* __restrict__ C) {                // [MROWS][OUT_F] f32
    __shared__ __align__(16) unsigned short lds[65536];   // 128 KiB

    const int tid  = threadIdx.x;
    const int lane = tid & 63;
    const int wave = tid >> 6;
    const int wr   = wave >> 2;   // 0..1
    const int wcn  = wave & 3;    // 0..3
    const int lr   = lane & 15;
    const int lg   = lane >> 4;

    // T1: bijective XCD swizzle, 512 wgs = 8 XCDs x 64
    const int bid = blockIdx.x;
    const int wg  = (bid & 7) * 64 + (bid >> 3);
    const int bm  = (wg >> 4) << 8;   // 32 M-tiles
    const int bn  = (wg & 15) << 8;   // 16 N-tiles

    // ---- staging source mapping (inverse swizzle on global addr) ----
    // round r: c = tid + r*512; LDS byte in half L = c*16; src = L ^ amt(L)
    int srow[2], skel[2];
#pragma unroll
    for (int r = 0; r < 2; ++r) {
        int c = tid + r * 512;
        int L = c * 16;
        int sw = L ^ (((L >> 7) & 7) << 4);
        srow[r] = sw >> 6;          // 0..255
        skel[r] = (sw & 63) >> 1;   // 0..31 elements
    }
    const unsigned short* pA0 = A + (size_t)(bm + srow[0]) * IN_F + skel[0];
    const unsigned short* pA1 = A + (size_t)(bm + srow[1]) * IN_F + skel[1];
    const unsigned short* pB0 = B + (size_t)(bn + srow[0]) * IN_F + skel[0];
    const unsigned short* pB1 = B + (size_t)(bn + srow[1]) * IN_F + skel[1];
    const int d0 = tid * 8, d1 = tid * 8 + 4096;   // ushort dest in half

#define STAGE_A(t, kh) do {                                                    \
        int _b = ((t) & 1) * 32768 + (kh) * 8192;                              \
        int _k = (t) * 64 + (kh) * 32;                                         \
        GLOAD16(pA0 + _k, &lds[_b + d0]);                                      \
        GLOAD16(pA1 + _k, &lds[_b + d1]); } while (0)
#define STAGE_B(t, kh) do {                                                    \
        int _b = ((t) & 1) * 32768 + 16384 + (kh) * 8192;                      \
        int _k = (t) * 64 + (kh) * 32;                                         \
        GLOAD16(pB0 + _k, &lds[_b + d0]);                                      \
        GLOAD16(pB1 + _k, &lds[_b + d1]); } while (0)

    // ---- swizzled ds_read lane offset (ushorts): X = (lr*64+lg*16)^amt(lr) ----
    const int laneoff = ((lr * 64 + lg * 16) ^ (((lr >> 1) & 7) << 4)) >> 1;
    const int arow = wr * 128;
    const int brow = wcn * 64;

    f32x4  acc[8][4] = {};
    bf16x8 af[4], bfv[4];

#define LOADB(b, kh) do {                                                      \
        int _base = (b) * 32768 + 16384 + (kh) * 8192 + brow * 32 + laneoff;   \
        bfv[0] = *reinterpret_cast<const bf16x8*>(&lds[_base]);                \
        bfv[1] = *reinterpret_cast<const bf16x8*>(&lds[_base + 512]);          \
        bfv[2] = *reinterpret_cast<const bf16x8*>(&lds[_base + 1024]);         \
        bfv[3] = *reinterpret_cast<const bf16x8*>(&lds[_base + 1536]); } while (0)
#define LOADA(b, kh, mq) do {                                                  \
        int _base = (b) * 32768 + (kh) * 8192 + (arow + (mq) * 64) * 32 + laneoff; \
        af[0] = *reinterpret_cast<const bf16x8*>(&lds[_base]);                 \
        af[1] = *reinterpret_cast<const bf16x8*>(&lds[_base + 512]);           \
        af[2] = *reinterpret_cast<const bf16x8*>(&lds[_base + 1024]);          \
        af[3] = *reinterpret_cast<const bf16x8*>(&lds[_base + 1536]); } while (0)

#define MFMA16(mq) do {                                                        \
        __builtin_amdgcn_s_setprio(1);                                         \
        _Pragma("unroll")                                                      \
        for (int mi = 0; mi < 4; ++mi)                                         \
            _Pragma("unroll")                                                  \
            for (int ni = 0; ni < 4; ++ni)                                     \
                acc[(mq) * 4 + mi][ni] = __builtin_amdgcn_mfma_f32_16x16x32_bf16( \
                    af[mi], bfv[ni], acc[(mq) * 4 + mi][ni], 0, 0, 0);         \
        __builtin_amdgcn_s_setprio(0); } while (0)

    // ---- prologue: tile0 all 4 halves + tile1 {B0,A0,B1}; vmcnt(6) => tile0 ----
    STAGE_B(0, 0); STAGE_A(0, 0); STAGE_B(0, 1); STAGE_A(0, 1);
    STAGE_B(1, 0); STAGE_A(1, 0); STAGE_B(1, 1);
    VMW(6);
    BAR();

#pragma unroll 2
    for (int t = 0; t < NT; ++t) {
        const int b = t & 1;
        // phase 1 (mq0, kh0): overwrite target A[kh1] of buf[(t+1)&1] was last
        // read at phase 4 of tile t-1 -> safe to issue now.
        LOADB(b, 0); LOADA(b, 0, 0);
        if (t + 1 < NT) STAGE_A(t + 1, 1);
        BAR(); LGKM0();
        MFMA16(0);
        BAR();
        // phase 2 (mq1, kh0): B[kh0] of this buf last read at phase 1.
        LOADA(b, 0, 1);
        if (t + 2 < NT) STAGE_B(t + 2, 0);
        BAR(); LGKM0();
        MFMA16(1);
        BAR();
        // phase 3 (mq0, kh1): A[kh0] last read at phase 2.
        LOADB(b, 1); LOADA(b, 1, 0);
        if (t + 2 < NT) STAGE_A(t + 2, 0);
        BAR(); LGKM0();
        MFMA16(0);
        BAR();
        // phase 4 (mq1, kh1): B[kh1] last read at phase 3. Counted vmcnt at the
        // K-tile boundary: 14 in flight -> 6 => tile t+1 fully landed.
        LOADA(b, 1, 1);
        if (t + 2 < NT) STAGE_B(t + 2, 1);
        BAR(); LGKM0();
        MFMA16(1);
        if (t < NT - 2)       { VMW(6); }
        else if (t == NT - 2) { VMW(0); }
        BAR();
    }

    // ---- epilogue: C/D layout col = lane&15, row = (lane>>4)*4 + j ----
#pragma unroll
    for (int a = 0; a < 8; ++a) {
        const int row0 = bm + wr * 128 + (a >> 2) * 64 + (a & 3) * 16 + lg * 4;
#pragma unroll
        for (int ni = 0; ni < 4; ++ni) {
            const int col = bn + wcn * 64 + ni * 16 + lr;
            const float bs = bias[col];
            float* cp = C + (size_t)row0 * OUT_F + col;
#pragma unroll
            for (int j = 0; j < 4; ++j)
                cp[(size_t)j * OUT_F] = acc[a][ni][j] + bs;
        }
    }
}

// ---------------------------------------------------------------------------
extern "C" void kernel_launch(void* const* d_in, const int* in_sizes, int n_in,
                              void* d_out, int out_size, void* d_ws, size_t ws_size,
                              hipStream_t stream) {
    const float* x      = (const float*)d_in[0];
    const int*   packed = (const int*)d_in[1];
    const float* absmax = (const float*)d_in[2];
    const float* bias   = (const float*)d_in[3];
    float* out = (float*)d_out;

    unsigned short* Wb = (unsigned short*)d_ws;                  // 32 MiB
    unsigned short* Xb = Wb + (size_t)OUT_F * IN_F;              // 64 MiB

    prep_kernel<<<2048, 256, 0, stream>>>(x, packed, absmax, Wb, Xb);
    gemm256_kernel<<<512, 512, 0, stream>>>(Xb, Wb, bias, out);
}

// Round 3
// 483.943 us; speedup vs baseline: 1.1499x; 1.0506x over previous
//
#include <hip/hip_runtime.h>
#include <hip/hip_bf16.h>
#include <stdint.h>

#define IN_F   4096
#define OUT_F  4096
#define MROWS  8192   // 4 * 2048
#define NT     64     // K-tiles of BK=64

typedef __bf16 bf16x8 __attribute__((ext_vector_type(8)));
typedef float  f32x4  __attribute__((ext_vector_type(4)));
typedef unsigned short ushort8v __attribute__((ext_vector_type(8)));

__device__ __constant__ float NF4_TAB[16] = {
    -1.0f, -0.6961928009986877f, -0.5250730514526367f, -0.39491748809814453f,
    -0.28444138169288635f, -0.18477343022823334f, -0.09105003625154495f, 0.0f,
    0.07958029955625534f, 0.16093020141124725f, 0.24611230194568634f, 0.33791524171829224f,
    0.44070982933044434f, 0.5626170039176941f, 0.7229568362236023f, 1.0f,
};

__device__ __forceinline__ unsigned short f2bf_rne(float f) {
    unsigned u = __builtin_bit_cast(unsigned, f);
    return (unsigned short)((u + 0x7FFFu + ((u >> 16) & 1u)) >> 16);
}

// ---------------------------------------------------------------------------
// Fused prep: blocks [0,512) dequant NF4 -> bf16 W; blocks [512,2048) f32->bf16 X
// ---------------------------------------------------------------------------
__global__ __launch_bounds__(256) void prep_kernel(
        const float* __restrict__ x, const int* __restrict__ packed,
        const float* __restrict__ absmax,
        unsigned short* __restrict__ Wb, unsigned short* __restrict__ Xb) {
    __shared__ float tab[16];
    if (threadIdx.x < 16) tab[threadIdx.x] = NF4_TAB[threadIdx.x];
    __syncthreads();

    const int bid = blockIdx.x;
    if (bid < 512) {
        const int ngroups = OUT_F * IN_F / 8;   // 2,097,152
        const int stride = 512 * 256;
        for (int g = bid * 256 + threadIdx.x; g < ngroups; g += stride) {
            int4 pv = reinterpret_cast<const int4*>(packed)[g];
            float am = absmax[g >> 3];
            ushort8v o;
            o[0] = f2bf_rne(tab[(pv.x >> 4) & 0xF] * am);
            o[1] = f2bf_rne(tab[ pv.x       & 0xF] * am);
            o[2] = f2bf_rne(tab[(pv.y >> 4) & 0xF] * am);
            o[3] = f2bf_rne(tab[ pv.y       & 0xF] * am);
            o[4] = f2bf_rne(tab[(pv.z >> 4) & 0xF] * am);
            o[5] = f2bf_rne(tab[ pv.z       & 0xF] * am);
            o[6] = f2bf_rne(tab[(pv.w >> 4) & 0xF] * am);
            o[7] = f2bf_rne(tab[ pv.w       & 0xF] * am);
            *reinterpret_cast<ushort8v*>(&Wb[(size_t)g * 8]) = o;
        }
    } else {
        const int ngroups = MROWS * IN_F / 8;   // 4,194,304
        const int stride = 1536 * 256;
        for (int g = (bid - 512) * 256 + threadIdx.x; g < ngroups; g += stride) {
            float4 v0 = reinterpret_cast<const float4*>(x)[2 * g];
            float4 v1 = reinterpret_cast<const float4*>(x)[2 * g + 1];
            ushort8v o;
            o[0] = f2bf_rne(v0.x); o[1] = f2bf_rne(v0.y);
            o[2] = f2bf_rne(v0.z); o[3] = f2bf_rne(v0.w);
            o[4] = f2bf_rne(v1.x); o[5] = f2bf_rne(v1.y);
            o[6] = f2bf_rne(v1.z); o[7] = f2bf_rne(v1.w);
            *reinterpret_cast<ushort8v*>(&Xb[(size_t)g * 8]) = o;
        }
    }
}

// ---------------------------------------------------------------------------
// 256x256 8-phase bf16 GEMM (T1+T2+T3+T4+T5), C = A[M][K] * B[N][K]^T + bias
// 512 threads = 8 waves (2 row x 4 col), per-wave out 128x64, BK=64.
// LDS 128 KiB: buf b in {0,1}: A-half kh: b*32768 + kh*8192 ushorts,
//                              B-half kh: b*32768 + 16384 + kh*8192.
// Swizzle (involution): byte X = L ^ (((L>>7)&7)<<4). Linear gload_lds dest +
// inverse-permuted global source + XOR'd ds_read address (rule #21).
// NOTE: no sched_barrier(0) in the phase wait — rule #18 applies only to
// inline-asm ds_read; pinning every phase is the m141 regression.
// ---------------------------------------------------------------------------
#define GLOAD16(gp, lp)                                                        \
    __builtin_amdgcn_global_load_lds(                                          \
        (const __attribute__((address_space(1))) void*)(gp),                   \
        (__attribute__((address_space(3))) void*)(lp), 16, 0, 0)

#define BAR()   __builtin_amdgcn_s_barrier()
#define LGKM()  asm volatile("s_waitcnt lgkmcnt(0)" ::: "memory")
#define VMW(n)  asm volatile("s_waitcnt vmcnt(" #n ")" ::: "memory")

__global__ __launch_bounds__(512) void gemm256_kernel(
        const unsigned short* __restrict__ A,   // [MROWS][IN_F] bf16
        const unsigned short* __restrict__ B,   // [OUT_F][IN_F] bf16
        const float* __restrict__ bias,
        float* __restrict__ C) {                // [MROWS][OUT_F] f32
    __shared__ __align__(16) unsigned short lds[65536];   // 128 KiB

    const int tid  = threadIdx.x;
    const int lane = tid & 63;
    const int wave = tid >> 6;
    const int wr   = wave >> 2;   // 0..1
    const int wcn  = wave & 3;    // 0..3
    const int lr   = lane & 15;
    const int lg   = lane >> 4;

    // T1: bijective XCD swizzle, 512 wgs = 8 XCDs x 64
    const int bid = blockIdx.x;
    const int wg  = (bid & 7) * 64 + (bid >> 3);
    const int bm  = (wg >> 4) << 8;   // 32 M-tiles
    const int bn  = (wg & 15) << 8;   // 16 N-tiles

    // staging source mapping (inverse swizzle on global addr)
    int srow[2], skel[2];
#pragma unroll
    for (int r = 0; r < 2; ++r) {
        int c = tid + r * 512;
        int L = c * 16;
        int sw = L ^ (((L >> 7) & 7) << 4);
        srow[r] = sw >> 6;
        skel[r] = (sw & 63) >> 1;
    }
    const unsigned short* pA0 = A + (size_t)(bm + srow[0]) * IN_F + skel[0];
    const unsigned short* pA1 = A + (size_t)(bm + srow[1]) * IN_F + skel[1];
    const unsigned short* pB0 = B + (size_t)(bn + srow[0]) * IN_F + skel[0];
    const unsigned short* pB1 = B + (size_t)(bn + srow[1]) * IN_F + skel[1];
    const int d0 = tid * 8, d1 = tid * 8 + 4096;

#define STAGE_A(t, kh) do {                                                    \
        int _b = ((t) & 1) * 32768 + (kh) * 8192;                              \
        int _k = (t) * 64 + (kh) * 32;                                         \
        GLOAD16(pA0 + _k, &lds[_b + d0]);                                      \
        GLOAD16(pA1 + _k, &lds[_b + d1]); } while (0)
#define STAGE_B(t, kh) do {                                                    \
        int _b = ((t) & 1) * 32768 + 16384 + (kh) * 8192;                      \
        int _k = (t) * 64 + (kh) * 32;                                         \
        GLOAD16(pB0 + _k, &lds[_b + d0]);                                      \
        GLOAD16(pB1 + _k, &lds[_b + d1]); } while (0)

    const int laneoff = ((lr * 64 + lg * 16) ^ (((lr >> 1) & 7) << 4)) >> 1;
    const int arow = wr * 128;
    const int brow = wcn * 64;

    f32x4  acc[8][4] = {};
    bf16x8 af[4], bfv[4];

#define LOADB(b, kh) do {                                                      \
        int _base = (b) * 32768 + 16384 + (kh) * 8192 + brow * 32 + laneoff;   \
        bfv[0] = *reinterpret_cast<const bf16x8*>(&lds[_base]);                \
        bfv[1] = *reinterpret_cast<const bf16x8*>(&lds[_base + 512]);          \
        bfv[2] = *reinterpret_cast<const bf16x8*>(&lds[_base + 1024]);         \
        bfv[3] = *reinterpret_cast<const bf16x8*>(&lds[_base + 1536]); } while (0)
#define LOADA(b, kh, mq) do {                                                  \
        int _base = (b) * 32768 + (kh) * 8192 + (arow + (mq) * 64) * 32 + laneoff; \
        af[0] = *reinterpret_cast<const bf16x8*>(&lds[_base]);                 \
        af[1] = *reinterpret_cast<const bf16x8*>(&lds[_base + 512]);           \
        af[2] = *reinterpret_cast<const bf16x8*>(&lds[_base + 1024]);          \
        af[3] = *reinterpret_cast<const bf16x8*>(&lds[_base + 1536]); } while (0)

#define MFMA16(mq) do {                                                        \
        __builtin_amdgcn_s_setprio(1);                                         \
        _Pragma("unroll")                                                      \
        for (int mi = 0; mi < 4; ++mi)                                         \
            _Pragma("unroll")                                                  \
            for (int ni = 0; ni < 4; ++ni)                                     \
                acc[(mq) * 4 + mi][ni] = __builtin_amdgcn_mfma_f32_16x16x32_bf16( \
                    af[mi], bfv[ni], acc[(mq) * 4 + mi][ni], 0, 0, 0);         \
        __builtin_amdgcn_s_setprio(0); } while (0)

    // phase bodies; S* = stage statement or nothing (tail peeling)
#define PHASE1(b, S) do { LOADB(b, 0); LOADA(b, 0, 0); S;                      \
        BAR(); LGKM(); MFMA16(0); BAR(); } while (0)
#define PHASE2(b, S) do { LOADA(b, 0, 1); S;                                   \
        BAR(); LGKM(); MFMA16(1); BAR(); } while (0)
#define PHASE3(b, S) do { LOADB(b, 1); LOADA(b, 1, 0); S;                      \
        BAR(); LGKM(); MFMA16(0); BAR(); } while (0)
#define PHASE4(b, S, V) do { LOADA(b, 1, 1); S;                                \
        BAR(); LGKM(); MFMA16(1); V; BAR(); } while (0)

    // prologue: tile0 all 4 halves + tile1 {B0,A0,B1}; vmcnt(6) => tile0 landed
    STAGE_B(0, 0); STAGE_A(0, 0); STAGE_B(0, 1); STAGE_A(0, 1);
    STAGE_B(1, 0); STAGE_A(1, 0); STAGE_B(1, 1);
    VMW(6);
    BAR();

    // steady state: t in [0, NT-2), all stages unconditional
#pragma unroll 2
    for (int t = 0; t < NT - 2; ++t) {
        const int b = t & 1;
        PHASE1(b, STAGE_A(t + 1, 1));
        PHASE2(b, STAGE_B(t + 2, 0));
        PHASE3(b, STAGE_A(t + 2, 0));
        PHASE4(b, STAGE_B(t + 2, 1), VMW(6));
    }
    // tile NT-2: only A(NT-1,1) remains to stage; drain all loads at the end
    PHASE1(0, STAGE_A(NT - 1, 1));
    PHASE2(0, );
    PHASE3(0, );
    PHASE4(0, , VMW(0));
    // tile NT-1: pure compute
    PHASE1(1, );
    PHASE2(1, );
    PHASE3(1, );
    PHASE4(1, , );

    // epilogue: C/D layout col = lane&15, row = (lane>>4)*4 + j
#pragma unroll
    for (int a = 0; a < 8; ++a) {
        const int row0 = bm + wr * 128 + (a >> 2) * 64 + (a & 3) * 16 + lg * 4;
#pragma unroll
        for (int ni = 0; ni < 4; ++ni) {
            const int col = bn + wcn * 64 + ni * 16 + lr;
            const float bs = bias[col];
            float* cp = C + (size_t)row0 * OUT_F + col;
#pragma unroll
            for (int j = 0; j < 4; ++j)
                cp[(size_t)j * OUT_F] = acc[a][ni][j] + bs;
        }
    }
}

// ---------------------------------------------------------------------------
extern "C" void kernel_launch(void* const* d_in, const int* in_sizes, int n_in,
                              void* d_out, int out_size, void* d_ws, size_t ws_size,
                              hipStream_t stream) {
    const float* x      = (const float*)d_in[0];
    const int*   packed = (const int*)d_in[1];
    const float* absmax = (const float*)d_in[2];
    const float* bias   = (const float*)d_in[3];
    float* out = (float*)d_out;

    unsigned short* Wb = (unsigned short*)d_ws;                  // 32 MiB
    unsigned short* Xb = Wb + (size_t)OUT_F * IN_F;              // 64 MiB

    prep_kernel<<<2048, 256, 0, stream>>>(x, packed, absmax, Wb, Xb);
    gemm256_kernel<<<512, 512, 0, stream>>>(Xb, Wb, bias, out);
}

// Round 5
// 481.989 us; speedup vs baseline: 1.1546x; 1.0041x over previous
//
#include <hip/hip_runtime.h>
#include <hip/hip_bf16.h>
#include <stdint.h>

#define IN_F   4096
#define OUT_F  4096
#define MROWS  8192   // 4 * 2048
#define NT     64     // K-tiles of BK=64

typedef __bf16 bf16x8 __attribute__((ext_vector_type(8)));
typedef float  f32x4  __attribute__((ext_vector_type(4)));
typedef unsigned short ushort8v __attribute__((ext_vector_type(8)));

__device__ __constant__ float NF4_TAB[16] = {
    -1.0f, -0.6961928009986877f, -0.5250730514526367f, -0.39491748809814453f,
    -0.28444138169288635f, -0.18477343022823334f, -0.09105003625154495f, 0.0f,
    0.07958029955625534f, 0.16093020141124725f, 0.24611230194568634f, 0.33791524171829224f,
    0.44070982933044434f, 0.5626170039176941f, 0.7229568362236023f, 1.0f,
};

__device__ __forceinline__ unsigned short f2bf_rne(float f) {
    unsigned u = __builtin_bit_cast(unsigned, f);
    return (unsigned short)((u + 0x7FFFu + ((u >> 16) & 1u)) >> 16);
}

// ---------------------------------------------------------------------------
// Fused prep: blocks [0,512) dequant NF4 -> bf16 W; blocks [512,2048) f32->bf16 X
// ---------------------------------------------------------------------------
__global__ __launch_bounds__(256) void prep_kernel(
        const float* __restrict__ x, const int* __restrict__ packed,
        const float* __restrict__ absmax,
        unsigned short* __restrict__ Wb, unsigned short* __restrict__ Xb) {
    __shared__ float tab[16];
    if (threadIdx.x < 16) tab[threadIdx.x] = NF4_TAB[threadIdx.x];
    __syncthreads();

    const int bid = blockIdx.x;
    if (bid < 512) {
        const int ngroups = OUT_F * IN_F / 8;   // 2,097,152
        const int stride = 512 * 256;
        for (int g = bid * 256 + threadIdx.x; g < ngroups; g += stride) {
            int4 pv = reinterpret_cast<const int4*>(packed)[g];
            float am = absmax[g >> 3];
            ushort8v o;
            o[0] = f2bf_rne(tab[(pv.x >> 4) & 0xF] * am);
            o[1] = f2bf_rne(tab[ pv.x       & 0xF] * am);
            o[2] = f2bf_rne(tab[(pv.y >> 4) & 0xF] * am);
            o[3] = f2bf_rne(tab[ pv.y       & 0xF] * am);
            o[4] = f2bf_rne(tab[(pv.z >> 4) & 0xF] * am);
            o[5] = f2bf_rne(tab[ pv.z       & 0xF] * am);
            o[6] = f2bf_rne(tab[(pv.w >> 4) & 0xF] * am);
            o[7] = f2bf_rne(tab[ pv.w       & 0xF] * am);
            *reinterpret_cast<ushort8v*>(&Wb[(size_t)g * 8]) = o;
        }
    } else {
        const int ngroups = MROWS * IN_F / 8;   // 4,194,304
        const int stride = 1536 * 256;
        for (int g = (bid - 512) * 256 + threadIdx.x; g < ngroups; g += stride) {
            float4 v0 = reinterpret_cast<const float4*>(x)[2 * g];
            float4 v1 = reinterpret_cast<const float4*>(x)[2 * g + 1];
            ushort8v o;
            o[0] = f2bf_rne(v0.x); o[1] = f2bf_rne(v0.y);
            o[2] = f2bf_rne(v0.z); o[3] = f2bf_rne(v0.w);
            o[4] = f2bf_rne(v1.x); o[5] = f2bf_rne(v1.y);
            o[6] = f2bf_rne(v1.z); o[7] = f2bf_rne(v1.w);
            *reinterpret_cast<ushort8v*>(&Xb[(size_t)g * 8]) = o;
        }
    }
}

// ---------------------------------------------------------------------------
// 256x256 8-phase bf16 GEMM, C = A[M][K] * B[N][K]^T + bias
// 512 threads = 8 waves (2 row x 4 col), per-wave out 128x64, BK=64.
// SCHEDULE (r4): single CLOSING barrier per phase — no opening BAR, no
// explicit lgkmcnt(0). Compiler emits counted lgkmcnt before each MFMA, so
// read-drain overlaps MFMA within-wave, and waves skew so one wave's reads
// hide under another's MFMA (m114 overlap, previously defeated by lockstep).
// All cross-wave hazards ride on the closing barriers + VMW(6)@P4:
//   - reads are lgkm-consumed before their wave reaches the closing BAR,
//     so post-BAR stages can't overwrite live reads (WAR safe);
//   - next-tile buffer readiness: VMW(6) before P4's BAR drains A(t+1,1)
//     and older => tile t+1 fully landed before any P1 read of it (RAW safe).
// Barriers are asm s_barrier with memory clobber => loads can't hoist across.
// ---------------------------------------------------------------------------
#define GLOAD16(gp, lp)                                                        \
    __builtin_amdgcn_global_load_lds(                                          \
        (const __attribute__((address_space(1))) void*)(gp),                   \
        (__attribute__((address_space(3))) void*)(lp), 16, 0, 0)

#define BARF()  asm volatile("s_barrier" ::: "memory")
#define VMW(n)  asm volatile("s_waitcnt vmcnt(" #n ")" ::: "memory")

__global__ __launch_bounds__(512) void gemm256_kernel(
        const unsigned short* __restrict__ A,   // [MROWS][IN_F] bf16
        const unsigned short* __restrict__ B,   // [OUT_F][IN_F] bf16
        const float* __restrict__ bias,
        float* __restrict__ C) {                // [MROWS][OUT_F] f32
    __shared__ __align__(16) unsigned short lds[65536];   // 128 KiB

    const int tid  = threadIdx.x;
    const int lane = tid & 63;
    const int wave = tid >> 6;
    const int wr   = wave >> 2;   // 0..1
    const int wcn  = wave & 3;    // 0..3
    const int lr   = lane & 15;
    const int lg   = lane >> 4;

    // T1: bijective XCD swizzle, 512 wgs = 8 XCDs x 64
    const int bid = blockIdx.x;
    const int wg  = (bid & 7) * 64 + (bid >> 3);
    const int bm  = (wg >> 4) << 8;   // 32 M-tiles
    const int bn  = (wg & 15) << 8;   // 16 N-tiles

    // staging source mapping (inverse swizzle on global addr)
    int srow[2], skel[2];
#pragma unroll
    for (int r = 0; r < 2; ++r) {
        int c = tid + r * 512;
        int L = c * 16;
        int sw = L ^ (((L >> 7) & 7) << 4);
        srow[r] = sw >> 6;
        skel[r] = (sw & 63) >> 1;
    }
    const unsigned short* pA0 = A + (size_t)(bm + srow[0]) * IN_F + skel[0];
    const unsigned short* pA1 = A + (size_t)(bm + srow[1]) * IN_F + skel[1];
    const unsigned short* pB0 = B + (size_t)(bn + srow[0]) * IN_F + skel[0];
    const unsigned short* pB1 = B + (size_t)(bn + srow[1]) * IN_F + skel[1];
    const int d0 = tid * 8, d1 = tid * 8 + 4096;

#define STAGE_A(t, kh) do {                                                    \
        int _b = ((t) & 1) * 32768 + (kh) * 8192;                              \
        int _k = (t) * 64 + (kh) * 32;                                         \
        GLOAD16(pA0 + _k, &lds[_b + d0]);                                      \
        GLOAD16(pA1 + _k, &lds[_b + d1]); } while (0)
#define STAGE_B(t, kh) do {                                                    \
        int _b = ((t) & 1) * 32768 + 16384 + (kh) * 8192;                      \
        int _k = (t) * 64 + (kh) * 32;                                         \
        GLOAD16(pB0 + _k, &lds[_b + d0]);                                      \
        GLOAD16(pB1 + _k, &lds[_b + d1]); } while (0)

    const int laneoff = ((lr * 64 + lg * 16) ^ (((lr >> 1) & 7) << 4)) >> 1;
    const int arow = wr * 128;
    const int brow = wcn * 64;

    f32x4  acc[8][4] = {};
    bf16x8 af[4], bfv[4];

#define LOADB(b, kh) do {                                                      \
        int _base = (b) * 32768 + 16384 + (kh) * 8192 + brow * 32 + laneoff;   \
        bfv[0] = *reinterpret_cast<const bf16x8*>(&lds[_base]);                \
        bfv[1] = *reinterpret_cast<const bf16x8*>(&lds[_base + 512]);          \
        bfv[2] = *reinterpret_cast<const bf16x8*>(&lds[_base + 1024]);         \
        bfv[3] = *reinterpret_cast<const bf16x8*>(&lds[_base + 1536]); } while (0)
#define LOADA(b, kh, mq) do {                                                  \
        int _base = (b) * 32768 + (kh) * 8192 + (arow + (mq) * 64) * 32 + laneoff; \
        af[0] = *reinterpret_cast<const bf16x8*>(&lds[_base]);                 \
        af[1] = *reinterpret_cast<const bf16x8*>(&lds[_base + 512]);           \
        af[2] = *reinterpret_cast<const bf16x8*>(&lds[_base + 1024]);          \
        af[3] = *reinterpret_cast<const bf16x8*>(&lds[_base + 1536]); } while (0)

#define MFMA16(mq) do {                                                        \
        __builtin_amdgcn_s_setprio(1);                                         \
        _Pragma("unroll")                                                      \
        for (int mi = 0; mi < 4; ++mi)                                         \
            _Pragma("unroll")                                                  \
            for (int ni = 0; ni < 4; ++ni)                                     \
                acc[(mq) * 4 + mi][ni] = __builtin_amdgcn_mfma_f32_16x16x32_bf16( \
                    af[mi], bfv[ni], acc[(mq) * 4 + mi][ni], 0, 0, 0);         \
        __builtin_amdgcn_s_setprio(0); } while (0)

    // phase bodies: reads -> stage -> MFMA (compiler counted-lgkm) -> BAR
#define PHASE1(b, S) do { LOADB(b, 0); LOADA(b, 0, 0); S;                      \
        MFMA16(0); BARF(); } while (0)
#define PHASE2(b, S) do { LOADA(b, 0, 1); S;                                   \
        MFMA16(1); BARF(); } while (0)
#define PHASE3(b, S) do { LOADB(b, 1); LOADA(b, 1, 0); S;                      \
        MFMA16(0); BARF(); } while (0)
#define PHASE4(b, S, V) do { LOADA(b, 1, 1); S;                                \
        MFMA16(1); V; BARF(); } while (0)

    // prologue: tile0 all 4 halves + tile1 {B0,A0,B1}; vmcnt(6) => tile0 landed
    STAGE_B(0, 0); STAGE_A(0, 0); STAGE_B(0, 1); STAGE_A(0, 1);
    STAGE_B(1, 0); STAGE_A(1, 0); STAGE_B(1, 1);
    VMW(6);
    BARF();

    // steady state: t in [0, NT-2), all stages unconditional
#pragma unroll 2
    for (int t = 0; t < NT - 2; ++t) {
        const int b = t & 1;
        PHASE1(b, STAGE_A(t + 1, 1));
        PHASE2(b, STAGE_B(t + 2, 0));
        PHASE3(b, STAGE_A(t + 2, 0));
        PHASE4(b, STAGE_B(t + 2, 1), VMW(6));
    }
    // tile NT-2: only A(NT-1,1) remains to stage; drain all loads at the end
    PHASE1(0, STAGE_A(NT - 1, 1));
    PHASE2(0, );
    PHASE3(0, );
    PHASE4(0, , VMW(0));
    // tile NT-1: pure compute
    PHASE1(1, );
    PHASE2(1, );
    PHASE3(1, );
    PHASE4(1, , );

    // epilogue: C/D layout col = lane&15, row = (lane>>4)*4 + j
#pragma unroll
    for (int a = 0; a < 8; ++a) {
        const int row0 = bm + wr * 128 + (a >> 2) * 64 + (a & 3) * 16 + lg * 4;
#pragma unroll
        for (int ni = 0; ni < 4; ++ni) {
            const int col = bn + wcn * 64 + ni * 16 + lr;
            const float bs = bias[col];
            float* cp = C + (size_t)row0 * OUT_F + col;
#pragma unroll
            for (int j = 0; j < 4; ++j)
                cp[(size_t)j * OUT_F] = acc[a][ni][j] + bs;
        }
    }
}

// ---------------------------------------------------------------------------
extern "C" void kernel_launch(void* const* d_in, const int* in_sizes, int n_in,
                              void* d_out, int out_size, void* d_ws, size_t ws_size,
                              hipStream_t stream) {
    const float* x      = (const float*)d_in[0];
    const int*   packed = (const int*)d_in[1];
    const float* absmax = (const float*)d_in[2];
    const float* bias   = (const float*)d_in[3];
    float* out = (float*)d_out;

    unsigned short* Wb = (unsigned short*)d_ws;                  // 32 MiB
    unsigned short* Xb = Wb + (size_t)OUT_F * IN_F;              // 64 MiB

    prep_kernel<<<2048, 256, 0, stream>>>(x, packed, absmax, Wb, Xb);
    gemm256_kernel<<<512, 512, 0, stream>>>(Xb, Wb, bias, out);
}